// Round 3
// baseline (101971.753 us; speedup 1.0000x reference)
//
#include <hip/hip_runtime.h>

#define BB 64
#define SS 256
#define TT 256

typedef unsigned short ushort_t;
typedef __attribute__((ext_vector_type(8))) __bf16 bf16x8;
typedef __attribute__((ext_vector_type(8))) short s16x8;
typedef __attribute__((ext_vector_type(16))) float f32x16;

union PkU { s16x8 s; bf16x8 b; };

__device__ __forceinline__ ushort_t f2bf(float f) {
    unsigned u = __float_as_uint(f);
    return (ushort_t)((u + 0x7FFFu + ((u >> 16) & 1u)) >> 16);
}
__device__ __forceinline__ float bf2f(ushort_t h) {
    return __uint_as_float(((unsigned)h) << 16);
}
__device__ __forceinline__ bf16x8 ldpk(const ushort_t* p) {
    PkU u; u.s = *(const s16x8*)p; return u.b;
}
__device__ __forceinline__ void cvt8(const float* f, bf16x8& hi, bf16x8& lo) {
    PkU H, L;
#pragma unroll
    for (int e = 0; e < 8; ++e) {
        ushort_t h = f2bf(f[e]);
        H.s[e] = (short)h;
        float r = f[e] - bf2f(h);
        L.s[e] = (short)f2bf(r);
    }
    hi = H.b; lo = L.b;
}
__device__ __forceinline__ void ldcvt(const float* p, bf16x8& hi, bf16x8& lo) {
    float4 a = *(const float4*)p;
    float4 b = *(const float4*)(p + 4);
    float f[8] = {a.x, a.y, a.z, a.w, b.x, b.y, b.z, b.w};
    cvt8(f, hi, lo);
}
__device__ __forceinline__ void mfma3(f32x16& acc, bf16x8 ah, bf16x8 al, bf16x8 bh, bf16x8 bl) {
    acc = __builtin_amdgcn_mfma_f32_32x32x16_bf16(ah, bh, acc, 0, 0, 0);
    acc = __builtin_amdgcn_mfma_f32_32x32x16_bf16(ah, bl, acc, 0, 0, 0);
    acc = __builtin_amdgcn_mfma_f32_32x32x16_bf16(al, bh, acc, 0, 0, 0);
}
__device__ __forceinline__ int crow(int r, int l) {
    return (r & 3) + ((r >> 2) << 3) + ((l >> 5) << 2);
}
__device__ __forceinline__ float fast_sigmoid(float x) { return 1.f / (1.f + __expf(-x)); }
__device__ __forceinline__ float fast_tanh(float x) { return 2.f / (1.f + __expf(-2.f * x)) - 1.f; }

// ---------------- weight transpose + hi/lo split + fragment pack ----------------
__global__ __launch_bounds__(256) void wsplit(
    const float* __restrict__ W, int ldw,
    ushort_t* __restrict__ pk_hi, ushort_t* __restrict__ pk_lo, int NT, int koff)
{
    __shared__ float tile[64][65];
    int k0 = blockIdx.x * 64, n0 = blockIdx.y * 64;
    int t = threadIdx.x;
    int r = t >> 2, cb = (t & 3) * 16;
    const float* src = W + (size_t)(k0 + r) * ldw + n0 + cb;
    float4 v0 = *(const float4*)(src);
    float4 v1 = *(const float4*)(src + 4);
    float4 v2 = *(const float4*)(src + 8);
    float4 v3 = *(const float4*)(src + 12);
    float vv[16] = {v0.x,v0.y,v0.z,v0.w, v1.x,v1.y,v1.z,v1.w, v2.x,v2.y,v2.z,v2.w, v3.x,v3.y,v3.z,v3.w};
#pragma unroll
    for (int i = 0; i < 16; ++i) tile[r][cb + i] = vv[i];
    __syncthreads();
#pragma unroll
    for (int i = 0; i < 2; ++i) {
        int gid = t + i * 256;
        int s_loc = gid >> 7, nt_loc = (gid >> 6) & 1, lane = gid & 63;
        int n_loc = nt_loc * 32 + (lane & 31);
        int kb = s_loc * 16 + (lane >> 5) * 8;
        float f[8];
#pragma unroll
        for (int e = 0; e < 8; ++e) f[e] = tile[kb + e][n_loc];
        bf16x8 hi, lo;
        cvt8(f, hi, lo);
        int s_glob = ((koff + k0) >> 4) + s_loc;
        int nt_glob = (n0 >> 5) + nt_loc;
        size_t off = ((size_t)(s_glob * NT + nt_glob) * 64 + lane) * 8;
        PkU H, L; H.b = hi; L.b = lo;
        *(s16x8*)(pk_hi + off) = H.s;
        *(s16x8*)(pk_lo + off) = L.s;
    }
}

// pack h0 [64][1024] fp32 -> fragment order hi/lo
__global__ __launch_bounds__(256) void pack64(
    const float* __restrict__ X, ushort_t* __restrict__ pk_hi, ushort_t* __restrict__ pk_lo)
{
    int gid = blockIdx.x * 256 + threadIdx.x;   // 8192
    int lane = gid & 63, mt = (gid >> 6) & 1, s = gid >> 7;
    int r = mt * 32 + (lane & 31);
    int k = s * 16 + (lane >> 5) * 8;
    bf16x8 hi, lo;
    ldcvt(X + (size_t)r * 1024 + k, hi, lo);
    PkU H, L; H.b = hi; L.b = lo;
    *(s16x8*)(pk_hi + (size_t)gid * 8) = H.s;
    *(s16x8*)(pk_lo + (size_t)gid * 8) = L.s;
}

// pack all dec_inputs [B][T][E] -> per-t fragment order, hi only
__global__ __launch_bounds__(512) void packdec(
    const float* __restrict__ dec, ushort_t* __restrict__ outp)
{
    int gid = blockIdx.x * 512 + threadIdx.x;   // 2,097,152
    int t = gid >> 13, g = gid & 8191;
    int s = g >> 7, mt = (g >> 6) & 1, lane = g & 63;
    int b = mt * 32 + (lane & 31);
    int e = s * 16 + ((lane >> 5) << 3);
    const float* p = dec + ((size_t)b * TT + t) * 1024 + e;
    float4 a = *(const float4*)p;
    float4 c = *(const float4*)(p + 4);
    float f[8] = {a.x, a.y, a.z, a.w, c.x, c.y, c.z, c.w};
    PkU H;
#pragma unroll
    for (int i = 0; i < 8; ++i) H.s[i] = (short)f2bf(f[i]);
    *(s16x8*)(outp + (size_t)gid * 8) = H.s;
}

// memory fp32 -> bf16 copy
__global__ __launch_bounds__(512) void memcvt(
    const float* __restrict__ src, ushort_t* __restrict__ dst)
{
    size_t i = ((size_t)blockIdx.x * 512 + threadIdx.x) * 8;
    float4 a = *(const float4*)(src + i);
    float4 c = *(const float4*)(src + i + 4);
    float f[8] = {a.x, a.y, a.z, a.w, c.x, c.y, c.z, c.w};
    PkU H;
#pragma unroll
    for (int e = 0; e < 8; ++e) H.s[e] = (short)f2bf(f[e]);
    *(s16x8*)(dst + i) = H.s;
}

// keys = memory @ W_mem -> bf16 [16384][1024]
__global__ __launch_bounds__(512) void gemm_keys(
    const float* __restrict__ Amem, const ushort_t* __restrict__ Bh,
    const ushort_t* __restrict__ Bl, ushort_t* __restrict__ keys)
{
    int tid = threadIdx.x;
    int w = tid >> 6, l = tid & 63;
    int job = blockIdx.x * 8 + w;    // 4096 = 256 mt x 16 nt
    int mt = job >> 4, nt = job & 15;
    int r0 = mt * 64, n0 = nt * 64;
    f32x16 acc[4];
#pragma unroll
    for (int i = 0; i < 4; ++i)
#pragma unroll
        for (int r = 0; r < 16; ++r) acc[i][r] = 0.f;
    for (int it = 0; it < 64; ++it) {
        bf16x8 ah[2], al[2], bh[2], bl[2];
#pragma unroll
        for (int tm = 0; tm < 2; ++tm)
            ldcvt(Amem + (size_t)(r0 + tm * 32 + (l & 31)) * 1024 + it * 16 + (l >> 5) * 8, ah[tm], al[tm]);
#pragma unroll
        for (int tn = 0; tn < 2; ++tn) {
            size_t boff = ((size_t)(it * 32 + nt * 2 + tn) * 64 + l) * 8;
            bh[tn] = ldpk(Bh + boff);
            bl[tn] = ldpk(Bl + boff);
        }
#pragma unroll
        for (int tm = 0; tm < 2; ++tm)
#pragma unroll
            for (int tn = 0; tn < 2; ++tn)
                mfma3(acc[tm * 2 + tn], ah[tm], al[tm], bh[tn], bl[tn]);
    }
#pragma unroll
    for (int tm = 0; tm < 2; ++tm)
#pragma unroll
        for (int tn = 0; tn < 2; ++tn)
#pragma unroll
            for (int r = 0; r < 16; ++r) {
                int row = r0 + tm * 32 + crow(r, l);
                int col = n0 + tn * 32 + (l & 31);
                keys[(size_t)row * 1024 + col] = f2bf(acc[tm * 2 + tn][r]);
            }
}

// out = attn_pk @ W_out + b_out, scattered to [B,T,V]
__global__ __launch_bounds__(512) void gemm_out(
    const ushort_t* __restrict__ Ah, const ushort_t* __restrict__ Al,
    const ushort_t* __restrict__ Bh, const ushort_t* __restrict__ Bl,
    const float* __restrict__ bias, float* __restrict__ outp)
{
    int tid = threadIdx.x;
    int w = tid >> 6, l = tid & 63;
    int job = blockIdx.x * 8 + w;    // 4096 = 256 t x 16 nt
    int t = job >> 4, nt = job & 15;
    f32x16 acc[4];
#pragma unroll
    for (int i = 0; i < 4; ++i)
#pragma unroll
        for (int r = 0; r < 16; ++r) acc[i][r] = 0.f;
    for (int it = 0; it < 64; ++it) {
        bf16x8 ah[2], al[2], bh[2], bl[2];
#pragma unroll
        for (int tm = 0; tm < 2; ++tm) {
            size_t g = ((size_t)t * 8192 + (size_t)it * 128 + tm * 64 + l) * 8;
            ah[tm] = ldpk(Ah + g);
            al[tm] = ldpk(Al + g);
        }
#pragma unroll
        for (int tn = 0; tn < 2; ++tn) {
            size_t boff = ((size_t)(it * 32 + nt * 2 + tn) * 64 + l) * 8;
            bh[tn] = ldpk(Bh + boff);
            bl[tn] = ldpk(Bl + boff);
        }
#pragma unroll
        for (int tm = 0; tm < 2; ++tm)
#pragma unroll
            for (int tn = 0; tn < 2; ++tn)
                mfma3(acc[tm * 2 + tn], ah[tm], al[tm], bh[tn], bl[tn]);
    }
#pragma unroll
    for (int tm = 0; tm < 2; ++tm)
#pragma unroll
        for (int tn = 0; tn < 2; ++tn)
#pragma unroll
            for (int r = 0; r < 16; ++r) {
                int b = tm * 32 + crow(r, l);
                int col = nt * 64 + tn * 32 + (l & 31);
                outp[((size_t)b * TT + t) * 1024 + col] = acc[tm * 2 + tn][r] + bias[col];
            }
}

// ---------------- grid barrier (device-scope, sense-free epoch) ----------------
__device__ __forceinline__ void gridbar(unsigned* bar, unsigned target) {
    __syncthreads();
    if (threadIdx.x == 0) {
        __hip_atomic_fetch_add(&bar[blockIdx.x & 7u], 1u, __ATOMIC_ACQ_REL, __HIP_MEMORY_SCOPE_AGENT);
        if (blockIdx.x == 0) {
            unsigned s;
            do {
                s = 0;
#pragma unroll
                for (int i = 0; i < 8; ++i)
                    s += __hip_atomic_load(&bar[i], __ATOMIC_ACQUIRE, __HIP_MEMORY_SCOPE_AGENT);
                if (s < target * 256u) __builtin_amdgcn_s_sleep(2);
            } while (s < target * 256u);
            __hip_atomic_store(&bar[8], target, __ATOMIC_RELEASE, __HIP_MEMORY_SCOPE_AGENT);
        }
        while (__hip_atomic_load(&bar[8], __ATOMIC_ACQUIRE, __HIP_MEMORY_SCOPE_AGENT) < target)
            __builtin_amdgcn_s_sleep(2);
    }
    __syncthreads();
}

// 8-wave in-block reduce of acc pairs into zb[0..2047]
__device__ __forceinline__ void red8(float* zb, const f32x16& a0, const f32x16& a1, int w, int l) {
    int col = l & 31;
    if (w < 4) {
        float* zq = zb + w * 2048;
#pragma unroll
        for (int r = 0; r < 16; ++r) {
            zq[crow(r, l) * 32 + col] = a0[r];
            zq[(32 + crow(r, l)) * 32 + col] = a1[r];
        }
    }
    __syncthreads();
    if (w >= 4) {
        float* zq = zb + (w - 4) * 2048;
#pragma unroll
        for (int r = 0; r < 16; ++r) {
            zq[crow(r, l) * 32 + col] += a0[r];
            zq[(32 + crow(r, l)) * 32 + col] += a1[r];
        }
    }
    __syncthreads();
    if (w == 0) {
#pragma unroll
        for (int i = 0; i < 32; ++i) zb[i * 64 + l] += zb[2 * 2048 + i * 64 + l];
    } else if (w == 1) {
#pragma unroll
        for (int i = 0; i < 32; ++i) zb[2048 + i * 64 + l] += zb[3 * 2048 + i * 64 + l];
    }
    __syncthreads();
    if (w == 0) {
#pragma unroll
        for (int i = 0; i < 32; ++i) zb[i * 64 + l] += zb[2048 + i * 64 + l];
    }
    __syncthreads();
}

// ---------------- the persistent decoder kernel ----------------
__global__ __launch_bounds__(512) void stepk(
    float* __restrict__ zp, float* __restrict__ qbuf, float* __restrict__ cstate,
    float* __restrict__ scoresb, unsigned* __restrict__ bar,
    const ushort_t* __restrict__ Wz_hi, const ushort_t* __restrict__ Wz_lo,
    const ushort_t* __restrict__ Wq_hi, const ushort_t* __restrict__ Wq_lo,
    const ushort_t* __restrict__ Wa_hi, const ushort_t* __restrict__ Wa_lo,
    const ushort_t* __restrict__ dec_pk,
    ushort_t* __restrict__ attn_hi, ushort_t* __restrict__ attn_lo,
    ushort_t* __restrict__ h_hi, ushort_t* __restrict__ h_lo,
    ushort_t* __restrict__ cx_hi, ushort_t* __restrict__ cx_lo,
    const ushort_t* __restrict__ keys, const ushort_t* __restrict__ memb,
    const float* __restrict__ c0, const float* __restrict__ b_lstm,
    const float* __restrict__ v_att, const int* __restrict__ mem_len)
{
    __shared__ float zbuf[4 * 2048];   // 32 KB
    __shared__ float align_s[256];
    __shared__ float cbuf[8][128];
    __shared__ float ctxv[256];
    __shared__ float red[16];

    const int tid = threadIdx.x;
    const int w = tid >> 6, l = tid & 63;
    const int bid = blockIdx.x;
    const int nt_z = bid >> 1, kh = bid & 1;
    unsigned ep = 0;

    for (int t = 0; t < TT; ++t) {
        // ================= Phase Z: z partials =================
        {
            f32x16 a0, a1;
#pragma unroll
            for (int r = 0; r < 16; ++r) { a0[r] = 0.f; a1[r] = 0.f; }
            int sbase = kh * 96 + w * 12;
            for (int i = 0; i < 12; ++i) {
                int s = sbase + i;
                size_t wo = ((size_t)(s * 128 + nt_z) * 64 + l) * 8;
                bf16x8 bh = ldpk(Wz_hi + wo);
                bf16x8 bl = ldpk(Wz_lo + wo);
                if (s < 64) {
                    const ushort_t* p = dec_pk + ((size_t)t * 8192 + (size_t)s * 128 + l) * 8;
                    bf16x8 x0 = ldpk(p), x1 = ldpk(p + 512);
                    a0 = __builtin_amdgcn_mfma_f32_32x32x16_bf16(x0, bh, a0, 0, 0, 0);
                    a0 = __builtin_amdgcn_mfma_f32_32x32x16_bf16(x0, bl, a0, 0, 0, 0);
                    a1 = __builtin_amdgcn_mfma_f32_32x32x16_bf16(x1, bh, a1, 0, 0, 0);
                    a1 = __builtin_amdgcn_mfma_f32_32x32x16_bf16(x1, bl, a1, 0, 0, 0);
                } else if (s < 128) {
                    if (t) {
                        size_t g = ((size_t)(t - 1) * 8192 + (size_t)(s - 64) * 128 + l) * 8;
                        bf16x8 ah0 = ldpk(attn_hi + g), al0 = ldpk(attn_lo + g);
                        bf16x8 ah1 = ldpk(attn_hi + g + 512), al1 = ldpk(attn_lo + g + 512);
                        mfma3(a0, ah0, al0, bh, bl);
                        mfma3(a1, ah1, al1, bh, bl);
                    }
                } else {
                    size_t g = ((size_t)(s - 128) * 128 + l) * 8;
                    bf16x8 hh0 = ldpk(h_hi + g), hl0 = ldpk(h_lo + g);
                    bf16x8 hh1 = ldpk(h_hi + g + 512), hl1 = ldpk(h_lo + g + 512);
                    mfma3(a0, hh0, hl0, bh, bl);
                    mfma3(a1, hh1, hl1, bh, bl);
                }
            }
            red8(zbuf, a0, a1, w, l);
            float* zpk = zp + (size_t)kh * 262144;
#pragma unroll
            for (int i = 0; i < 4; ++i) {
                int el = tid + i * 512;
                zpk[(size_t)(el >> 5) * 4096 + nt_z * 32 + (el & 31)] = zbuf[el];
            }
        }
        gridbar(bar, ++ep);

        // ================= Phase G: gates + pack h =================
        if (tid < 32) {
            int g = bid * 32 + tid;
            int s = g >> 7, mt = (g >> 6) & 1, lane = g & 63;
            int b = mt * 32 + (lane & 31);
            int u0 = s * 16 + ((lane >> 5) << 3);
            float zz[4][8];
#pragma unroll
            for (int gg = 0; gg < 4; ++gg) {
                float4 b0 = *(const float4*)(b_lstm + gg * 1024 + u0);
                float4 b1 = *(const float4*)(b_lstm + gg * 1024 + u0 + 4);
                zz[gg][0] = b0.x; zz[gg][1] = b0.y; zz[gg][2] = b0.z; zz[gg][3] = b0.w;
                zz[gg][4] = b1.x; zz[gg][5] = b1.y; zz[gg][6] = b1.z; zz[gg][7] = b1.w;
#pragma unroll
                for (int k2 = 0; k2 < 2; ++k2) {
                    const float* p = zp + (size_t)k2 * 262144 + (size_t)b * 4096 + gg * 1024 + u0;
                    float4 x0 = *(const float4*)p;
                    float4 x1 = *(const float4*)(p + 4);
                    zz[gg][0] += x0.x; zz[gg][1] += x0.y; zz[gg][2] += x0.z; zz[gg][3] += x0.w;
                    zz[gg][4] += x1.x; zz[gg][5] += x1.y; zz[gg][6] += x1.z; zz[gg][7] += x1.w;
                }
            }
            const float* cin = t ? cstate : c0;
            float hv[8];
#pragma unroll
            for (int e = 0; e < 8; ++e) {
                float ig = fast_sigmoid(zz[0][e]);
                float fg = fast_sigmoid(zz[1][e]);
                float gg_ = fast_tanh(zz[2][e]);
                float og = fast_sigmoid(zz[3][e]);
                float c = fg * cin[(size_t)b * 1024 + u0 + e] + ig * gg_;
                cstate[(size_t)b * 1024 + u0 + e] = c;
                hv[e] = og * fast_tanh(c);
            }
            bf16x8 hi, lo;
            cvt8(hv, hi, lo);
            PkU H, L; H.b = hi; L.b = lo;
            *(s16x8*)(h_hi + (size_t)g * 8) = H.s;
            *(s16x8*)(h_lo + (size_t)g * 8) = L.s;
        }
        gridbar(bar, ++ep);

        // ================= Phase Q: q = h @ Wq =================
        if (bid < 32) {
            f32x16 a0, a1;
#pragma unroll
            for (int r = 0; r < 16; ++r) { a0[r] = 0.f; a1[r] = 0.f; }
            for (int i = 0; i < 8; ++i) {
                int s = w * 8 + i;
                size_t g = ((size_t)s * 128 + l) * 8;
                bf16x8 hh0 = ldpk(h_hi + g), hl0 = ldpk(h_lo + g);
                bf16x8 hh1 = ldpk(h_hi + g + 512), hl1 = ldpk(h_lo + g + 512);
                size_t boff = ((size_t)(s * 32 + bid) * 64 + l) * 8;
                bf16x8 bh = ldpk(Wq_hi + boff), bl = ldpk(Wq_lo + boff);
                mfma3(a0, hh0, hl0, bh, bl);
                mfma3(a1, hh1, hl1, bh, bl);
            }
            red8(zbuf, a0, a1, w, l);
#pragma unroll
            for (int i = 0; i < 4; ++i) {
                int el = tid + i * 512;
                qbuf[(size_t)(el >> 5) * 1024 + bid * 32 + (el & 31)] = zbuf[el];
            }
        }
        gridbar(bar, ++ep);

        // ================= Phase S: Bahdanau scores =================
        {
            int job = bid * 8 + w;          // 2048 = 64 b x 32 sblk
            int b = job >> 5, sblk = job & 31;
            float qv[16], vv[16];
#pragma unroll
            for (int i = 0; i < 4; ++i) {
                float4 q4 = *(const float4*)(qbuf + (size_t)b * 1024 + l * 16 + i * 4);
                float4 v4 = *(const float4*)(v_att + l * 16 + i * 4);
                qv[i*4] = q4.x; qv[i*4+1] = q4.y; qv[i*4+2] = q4.z; qv[i*4+3] = q4.w;
                vv[i*4] = v4.x; vv[i*4+1] = v4.y; vv[i*4+2] = v4.z; vv[i*4+3] = v4.w;
            }
            int ml = mem_len[b];
            for (int rr = 0; rr < 8; ++rr) {
                int s = sblk * 8 + rr;
                const ushort_t* kp = keys + ((size_t)(b * SS + s) * 1024) + l * 16;
                s16x8 k0 = *(const s16x8*)kp;
                s16x8 k1 = *(const s16x8*)(kp + 8);
                float acc = 0.f;
#pragma unroll
                for (int e = 0; e < 8; ++e)
                    acc += fast_tanh(bf2f((ushort_t)k0[e]) + qv[e]) * vv[e];
#pragma unroll
                for (int e = 0; e < 8; ++e)
                    acc += fast_tanh(bf2f((ushort_t)k1[e]) + qv[8 + e]) * vv[8 + e];
#pragma unroll
                for (int off = 32; off; off >>= 1) acc += __shfl_xor(acc, off);
                if (l == 0) scoresb[b * SS + s] = (s < ml) ? acc : -1e9f;
            }
        }
        gridbar(bar, ++ep);

        // ================= Phase C: softmax + context + pack ctx =================
        {
            int b = bid >> 2, dpair = bid & 3;
            int ss = tid & 255;
            float sc = scoresb[b * SS + ss];
            float m = sc;
#pragma unroll
            for (int off = 32; off; off >>= 1) m = fmaxf(m, __shfl_xor(m, off));
            if (l == 0) red[w] = m;
            __syncthreads();
            m = fmaxf(fmaxf(fmaxf(red[0], red[1]), fmaxf(red[2], red[3])),
                      fmaxf(fmaxf(red[4], red[5]), fmaxf(red[6], red[7])));
            float e = __expf(sc - m);
            if (tid < 256) align_s[ss] = e;
            float su = e;
#pragma unroll
            for (int off = 32; off; off >>= 1) su += __shfl_xor(su, off);
            if (l == 0) red[8 + w] = su;
            __syncthreads();
            float rinv = 1.f / (red[8] + red[9] + red[10] + red[11]);
            int dchunk = dpair * 2 + (w >> 2), sq = w & 3;
            int d0 = dchunk * 128 + l * 2;
            float c0a = 0.f, c1a = 0.f;
            for (int i = 0; i < 64; ++i) {
                int s = sq * 64 + i;
                float al = align_s[s];
                unsigned mv = *(const unsigned*)(memb + ((size_t)(b * SS + s) * 1024) + d0);
                c0a += al * bf2f((ushort_t)(mv & 0xffffu));
                c1a += al * bf2f((ushort_t)(mv >> 16));
            }
            cbuf[w][l * 2] = c0a;
            cbuf[w][l * 2 + 1] = c1a;
            __syncthreads();
            if (tid < 256) {
                int dc = tid >> 7, idx = tid & 127;
                ctxv[tid] = (cbuf[dc * 4][idx] + cbuf[dc * 4 + 1][idx] +
                             cbuf[dc * 4 + 2][idx] + cbuf[dc * 4 + 3][idx]) * rinv;
            }
            __syncthreads();
            if (tid < 32) {
                float f[8];
#pragma unroll
                for (int e2 = 0; e2 < 8; ++e2) f[e2] = ctxv[tid * 8 + e2];
                bf16x8 hi, lo;
                cvt8(f, hi, lo);
                int dg = dpair * 256 + tid * 8;
                int sg = dg >> 4, hih = (dg >> 3) & 1;
                int laneg = (hih << 5) + (b & 31);
                int mtg = b >> 5;
                size_t g = ((size_t)sg * 128 + mtg * 64 + laneg) * 8;
                PkU H, L; H.b = hi; L.b = lo;
                *(s16x8*)(cx_hi + g) = H.s;
                *(s16x8*)(cx_lo + g) = L.s;
            }
        }
        gridbar(bar, ++ep);

        // ================= Phase A: attn = [h;ctx] @ Wa, pack =================
        if (bid < 32) {
            f32x16 a0, a1;
#pragma unroll
            for (int r = 0; r < 16; ++r) { a0[r] = 0.f; a1[r] = 0.f; }
            for (int i = 0; i < 16; ++i) {
                int s = w * 16 + i;     // 0..127
                const ushort_t* ph = (s < 64) ? h_hi : cx_hi;
                const ushort_t* pl = (s < 64) ? h_lo : cx_lo;
                int sl = s & 63;
                size_t g = ((size_t)sl * 128 + l) * 8;
                bf16x8 x0h = ldpk(ph + g), x0l = ldpk(pl + g);
                bf16x8 x1h = ldpk(ph + g + 512), x1l = ldpk(pl + g + 512);
                size_t boff = ((size_t)(s * 32 + bid) * 64 + l) * 8;
                bf16x8 bh = ldpk(Wa_hi + boff), bl = ldpk(Wa_lo + boff);
                mfma3(a0, x0h, x0l, bh, bl);
                mfma3(a1, x1h, x1l, bh, bl);
            }
            red8(zbuf, a0, a1, w, l);
            if (tid < 256) {
                int sl_loc = tid >> 7, mtg = (tid >> 6) & 1, laneg = tid & 63;
                int b = mtg * 32 + (laneg & 31);
                int lc = sl_loc * 16 + ((laneg >> 5) << 3);
                float f[8];
#pragma unroll
                for (int e2 = 0; e2 < 8; ++e2) f[e2] = zbuf[b * 32 + lc + e2];
                bf16x8 hi, lo;
                cvt8(f, hi, lo);
                int sg = bid * 2 + sl_loc;
                size_t g = ((size_t)t * 8192 + (size_t)sg * 128 + mtg * 64 + laneg) * 8;
                PkU H, L; H.b = hi; L.b = lo;
                *(s16x8*)(attn_hi + g) = H.s;
                *(s16x8*)(attn_lo + g) = L.s;
            }
        }
        gridbar(bar, ++ep);
    }
}

extern "C" void kernel_launch(void* const* d_in, const int* in_sizes, int n_in,
                              void* d_out, int out_size, void* d_ws, size_t ws_size,
                              hipStream_t stream)
{
    const float* memory  = (const float*)d_in[0];
    const float* dec     = (const float*)d_in[1];
    const float* h0      = (const float*)d_in[2];
    const float* c0      = (const float*)d_in[3];
    const float* W_lstm  = (const float*)d_in[4];
    const float* U_lstm  = (const float*)d_in[5];
    const float* b_lstm  = (const float*)d_in[6];
    const float* W_mem   = (const float*)d_in[7];
    const float* W_query = (const float*)d_in[8];
    const float* v_att   = (const float*)d_in[9];
    const float* W_attn  = (const float*)d_in[10];
    const float* W_out   = (const float*)d_in[11];
    const float* b_out   = (const float*)d_in[12];
    const int*   mem_len = (const int*)d_in[13];
    float* out = (float*)d_out;

    float* ws = (float*)d_ws;
    float* zp      = ws;                        // 524,288
    float* qbuf    = zp + 524288;               //  65,536
    float* cstate  = qbuf + 65536;              //  65,536
    float* scoresb = cstate + 65536;            //  16,384
    unsigned* bar  = (unsigned*)(scoresb + 16384);   // 16

    ushort_t* us    = (ushort_t*)(bar + 16);
    ushort_t* Wz_hi = us;                        // 12,582,912
    ushort_t* Wz_lo = Wz_hi + 12582912;
    ushort_t* Wq_hi = Wz_lo + 12582912;          //  1,048,576
    ushort_t* Wq_lo = Wq_hi + 1048576;
    ushort_t* Wa_hi = Wq_lo + 1048576;           //  2,097,152
    ushort_t* Wa_lo = Wa_hi + 2097152;
    ushort_t* Wo_hi = Wa_lo + 2097152;           //  1,048,576
    ushort_t* Wo_lo = Wo_hi + 1048576;
    ushort_t* Wm_hi = Wo_lo + 1048576;           //  1,048,576
    ushort_t* Wm_lo = Wm_hi + 1048576;
    ushort_t* dec_pk  = Wm_lo + 1048576;         // 16,777,216
    ushort_t* attn_hi = dec_pk + 16777216;       // 16,777,216
    ushort_t* attn_lo = attn_hi + 16777216;
    ushort_t* h_hi  = attn_lo + 16777216;        //     65,536
    ushort_t* h_lo  = h_hi + 65536;
    ushort_t* cx_hi = h_lo + 65536;
    ushort_t* cx_lo = cx_hi + 65536;
    ushort_t* keysb = cx_lo + 65536;             // 16,777,216
    ushort_t* memb  = keysb + 16777216;          // 16,777,216

    hipMemsetAsync(bar, 0, 64, stream);

    // weight packing
    wsplit<<<dim3(32, 64), 256, 0, stream>>>(W_lstm, 4096, Wz_hi, Wz_lo, 128, 0);
    wsplit<<<dim3(16, 64), 256, 0, stream>>>(U_lstm, 4096, Wz_hi, Wz_lo, 128, 2048);
    wsplit<<<dim3(16, 16), 256, 0, stream>>>(W_query, 1024, Wq_hi, Wq_lo, 32, 0);
    wsplit<<<dim3(32, 16), 256, 0, stream>>>(W_attn, 1024, Wa_hi, Wa_lo, 32, 0);
    wsplit<<<dim3(16, 16), 256, 0, stream>>>(W_out, 1024, Wo_hi, Wo_lo, 32, 0);
    wsplit<<<dim3(16, 16), 256, 0, stream>>>(W_mem, 1024, Wm_hi, Wm_lo, 32, 0);
    pack64<<<32, 256, 0, stream>>>(h0, h_hi, h_lo);
    packdec<<<4096, 512, 0, stream>>>(dec, dec_pk);
    memcvt<<<4096, 512, 0, stream>>>(memory, memb);
    gemm_keys<<<512, 512, 0, stream>>>(memory, Wm_hi, Wm_lo, keysb);

    // the whole 256-step decoder in one persistent kernel
    stepk<<<256, 512, 0, stream>>>(
        zp, qbuf, cstate, scoresb, bar,
        Wz_hi, Wz_lo, Wq_hi, Wq_lo, Wa_hi, Wa_lo,
        dec_pk, attn_hi, attn_lo, h_hi, h_lo, cx_hi, cx_lo,
        keysb, memb, c0, b_lstm, v_att, mem_len);

    // out = attn @ W_out + b_out
    gemm_out<<<512, 512, 0, stream>>>(attn_hi, attn_lo, Wo_hi, Wo_lo, b_out, out);
}